// Round 8
// baseline (198.487 us; speedup 1.0000x reference)
//
#include <hip/hip_runtime.h>
#include <hip/hip_bf16.h>
#include <math.h>

// Problem constants (fixed by setup_inputs)
#define BATCH 512
#define NADV  16
#define NROWS (BATCH*NADV)     // 8192
#define DS    32
#define DO    32
#define DIM   64               // DS + DO
#define HID   128
#define WCOLS (DIM*HID)        // 8192 columns of hw2
#define LSTR  136              // padded f16 LDS row stride (2-way bank aliasing)
#define PACK_BLOCKS 276

typedef _Float16 half8 __attribute__((ext_vector_type(8)));
typedef float floatx4 __attribute__((ext_vector_type(4)));

__device__ inline void async_ld16(void* lds, const void* g) {
    __builtin_amdgcn_global_load_lds(
        (const __attribute__((address_space(1))) void*)g,
        (__attribute__((address_space(3))) void*)lds, 16, 0, 0);
}

// ---------------------------------------------------------------------------
// Kernel PREP (fused): blocks [0,276) pack weights into MFMA-native f16
// chunks (coalesced 512-B row reads via LDS tile); blocks [276,788) build
// h = relu(x@hw1+hb1) (x formed in LDS from obs/latent; not materialized).
// Packed layout: chunk(ct,kt)[lane*8+e] = W[kt*32+(lane>>4)*8+e][ct*16+(lane&15)]
// so a wave's B-fragment load is ONE contiguous 1 KB burst.
// ---------------------------------------------------------------------------
__global__ __launch_bounds__(256)
void k_prep(const float* __restrict__ obs, const float* __restrict__ latent,
            const float* __restrict__ hw1, const float* __restrict__ hb1,
            const float* __restrict__ hw2, const float* __restrict__ vw1,
            const float* __restrict__ vw2, const float* __restrict__ aw1,
            const float* __restrict__ aw2,
            _Float16* __restrict__ hf,
            _Float16* __restrict__ w2p, _Float16* __restrict__ vw1p,
            _Float16* __restrict__ vw2p, _Float16* __restrict__ aw1p,
            _Float16* __restrict__ aw2p) {
    __shared__ __align__(16) float smem[32 * 132];   // 16.9 KB
    int b = blockIdx.x;
    int tid = threadIdx.x;
    if (b < PACK_BLOCKS) {
        const float* src; _Float16* dst; int N, Kt, jb, kt;
        if (b < 256)      { src = hw2; dst = w2p;  N = WCOLS; Kt = 4; jb = b >> 2; kt = b & 3; }
        else if (b < 260) { src = vw1; dst = vw1p; N = HID;   Kt = 4; jb = 0; kt = b - 256; }
        else if (b < 264) { src = vw2; dst = vw2p; N = HID;   Kt = 4; jb = 0; kt = b - 260; }
        else if (b < 272) { src = aw1; dst = aw1p; N = HID;   Kt = 8; jb = 0; kt = b - 264; }
        else              { src = aw2; dst = aw2p; N = HID;   Kt = 4; jb = 0; kt = b - 272; }
        // coalesced read: 32 k-rows x 128 j-cols (512 B contiguous per row)
        for (int i = tid; i < 32 * 32; i += 256) {
            int r = i >> 5, c4 = (i & 31) * 4;
            *(float4*)&smem[r * 132 + c4] =
                *(const float4*)(src + (size_t)(kt * 32 + r) * N + jb * 128 + c4);
        }
        __syncthreads();
        // write 8 chunks (ctl 0..7), each 1 KB, fully contiguous stores
        for (int i = tid; i < 8 * 64; i += 256) {
            int ctl = i >> 6, lane = i & 63;
            int ct = jb * 8 + ctl;
            int rbase = (lane >> 4) * 8, cc = ctl * 16 + (lane & 15);
            half8 v;
#pragma unroll
            for (int e = 0; e < 8; ++e) v[e] = (_Float16)smem[(rbase + e) * 132 + cc];
            *(half8*)(dst + ((size_t)ct * Kt + kt) * 512 + lane * 8) = v;
        }
    } else {
        // input_h: 16 rows, h = relu(x @ hw1 + hb1)
        int n0 = (b - PACK_BLOCKS) * 16;
        float* xs = smem;   // [16][DIM]
        for (int idx = tid; idx < 16 * DIM; idx += 256) {
            int r = idx >> 6, d = idx & 63;
            int n = n0 + r;
            // reference pairs obs[n % B] with latent_flat[n] (torch .repeat
            // tiles the batch dim; reshape(-1,DO) row-major) — exact.
            xs[r * DIM + d] = (d < DS) ? obs[(n & (BATCH - 1)) * DS + d]
                                       : latent[(size_t)n * DO + (d - DS)];
        }
        __syncthreads();
        int j = tid & 127, hh = tid >> 7;   // hh: rows hh*8..+8
        float acc[8];
        float bb = hb1[j];
#pragma unroll
        for (int r = 0; r < 8; ++r) acc[r] = bb;
        for (int d = 0; d < DIM; ++d) {
            float w = hw1[d * HID + j];
#pragma unroll
            for (int r = 0; r < 8; ++r)
                acc[r] = fmaf(xs[(hh * 8 + r) * DIM + d], w, acc[r]);
        }
#pragma unroll
        for (int r = 0; r < 8; ++r)
            hf[(size_t)(n0 + hh * 8 + r) * HID + j] = (_Float16)fmaxf(acc[r], 0.f);
    }
}

// ---------------------------------------------------------------------------
// Kernel B: block = 128 rows x 16 emb-cols x ALL 64 d (d-reduce block-local).
// SINGLE-buffer 32 KB LDS -> 4 blocks/CU (launch_bounds 512,8): barrier
// drains are hidden by other resident blocks' compute (m114 co-schedule),
// which explicit dbuf at 2 blocks/CU could not do (r7 regression).
// x/bias come per-iter direct from L2-warm global (quad-broadcast loads).
// Grid = 64 rt x 8 jt (jt = b&7: XCD-local B reuse).
// ---------------------------------------------------------------------------
__global__ __launch_bounds__(512, 8)
void k_hyper_mfma(const float* __restrict__ obs, const float* __restrict__ latent,
                  const _Float16* __restrict__ hf, const _Float16* __restrict__ w2p,
                  const float* __restrict__ hb2,
                  _Float16* __restrict__ embf, _Float16* __restrict__ emeanf) {
    __shared__ __align__(16) _Float16 Bs[8][4][512];  // 32 KB single buffer
    int b  = blockIdx.x;
    int jt = b & 7;          // emb col-tile (16 cols) — XCD-aligned B reuse
    int rt = b >> 3;         // row-tile: rows [rt*128, +128)
    int n0 = rt * 128;
    int j0 = jt * 16;
    int tid = threadIdx.x;
    int wave = tid >> 6, lane = tid & 63;
    int l15 = lane & 15, quad = lane >> 4;
    int row_lo = n0 + wave * 16 + quad * 4;   // this lane's 4 C-rows

    // A fragments: wave w owns rows [n0+w*16, +16) (= batch rt*8+w)
    half8 af[4];
    {
        const _Float16* arow = hf + (size_t)(n0 + wave * 16 + l15) * HID;
#pragma unroll
        for (int ks = 0; ks < 4; ++ks)
            af[ks] = *(const half8*)(arow + ks * 32 + quad * 8);
    }

    float emb_acc[4] = {0.f, 0.f, 0.f, 0.f};

#pragma unroll
    for (int d8 = 0; d8 < 8; ++d8) {
        {   // stage B: wave w stages d-tile (d8*8+w)'s chunk as 4 x 1 KB bursts
            int ct = (d8 * 8 + wave) * 8 + jt;
            const _Float16* src = w2p + (size_t)ct * 2048 + lane * 8;
            _Float16* dst = &Bs[wave][0][0];
#pragma unroll
            for (int kt = 0; kt < 4; ++kt)
                async_ld16(dst + kt * 512, src + kt * 512);
        }
        __syncthreads();   // DMA drained; prev iter's consumers done

        // x for this iter: 2 float4 per row, quad-broadcast (16 lanes share)
        float xr[4][8];
#pragma unroll
        for (int r = 0; r < 4; ++r) {
            int row = row_lo + r;
            const float* p = (d8 < 4)
                ? obs + (size_t)(row & (BATCH - 1)) * DS + d8 * 8
                : latent + (size_t)row * DO + (d8 - 4) * 8;
            float4 t0 = *(const float4*)p;
            float4 t1 = *(const float4*)(p + 4);
            xr[r][0] = t0.x; xr[r][1] = t0.y; xr[r][2] = t0.z; xr[r][3] = t0.w;
            xr[r][4] = t1.x; xr[r][5] = t1.y; xr[r][6] = t1.z; xr[r][7] = t1.w;
        }

#pragma unroll
        for (int dd = 0; dd < 8; ++dd) {
            int d = d8 * 8 + dd;
            float bb = hb2[d * HID + j0 + l15];   // coalesced 64-B wave load
            floatx4 acc = {bb, bb, bb, bb};
#pragma unroll
            for (int ks = 0; ks < 4; ++ks) {
                half8 bfr = *(const half8*)&Bs[dd][ks][lane * 8];
                acc = __builtin_amdgcn_mfma_f32_16x16x32_f16(af[ks], bfr, acc, 0, 0, 0);
            }
            // D: row = wave*16 + quad*4 + reg, col = j0 + l15
#pragma unroll
            for (int reg = 0; reg < 4; ++reg)
                emb_acc[reg] = fmaf(xr[reg][dd], fmaxf(acc[reg], 0.f), emb_acc[reg]);
        }
        __syncthreads();   // done consuming Bs; safe to restage
    }

    // epilogue: tanh -> embf; wave = one batch -> column means direct
    float e[4];
#pragma unroll
    for (int reg = 0; reg < 4; ++reg) {
        e[reg] = tanhf(emb_acc[reg]);
        embf[(size_t)(n0 + wave * 16 + quad * 4 + reg) * HID + j0 + l15] =
            (_Float16)e[reg];
    }
    float s = e[0] + e[1] + e[2] + e[3];
    s += __shfl_xor(s, 16, 64);
    s += __shfl_xor(s, 32, 64);
    if (quad == 0)
        emeanf[(size_t)(rt * 8 + wave) * HID + j0 + l15] = (_Float16)(s * (1.f / 16));
}

// ---------------------------------------------------------------------------
// Kernel T (fused tail), 512 blocks x 16 rows (1 softmax group each).
// 4 barriers total: A-frags load DIRECT from global (no LDS stage);
// a2 writes a third buffer (no WAR barrier); scores+softmax in wave 0
// via shfl (no scr/satt LDS stages).
// ---------------------------------------------------------------------------
__global__ __launch_bounds__(512, 4)
void k_tail(const _Float16* __restrict__ embf, const _Float16* __restrict__ emeanf,
            const _Float16* __restrict__ vw1p, const float* __restrict__ vb1,
            const _Float16* __restrict__ vw2p, const float* __restrict__ vb2,
            const _Float16* __restrict__ aw1p, const float* __restrict__ ab1,
            const _Float16* __restrict__ aw2p, const float* __restrict__ ab2,
            const float* __restrict__ aw3, const float* __restrict__ ab3,
            float* __restrict__ out) {
    __shared__ _Float16 tAs[16][LSTR];
    __shared__ _Float16 tBs[16][LSTR];
    __shared__ _Float16 tCs[16][LSTR];
    __shared__ float att[16];
    int g = blockIdx.x;       // batch 0..511
    int n0 = g * 16;
    int tid = threadIdx.x;
    int wave = tid >> 6, lane = tid & 63, l15 = lane & 15, quad = lane >> 4;
    int ct = wave;            // wave owns col-tile ct of 8

    // A-fragments direct from global (L2-warm): row = l15, 16-B chunk by quad
    half8 av[4], amean[4];
    {
        const _Float16* erow = embf + (size_t)(n0 + l15) * HID;
        // mean_rep[n] = emb_mean[n % 512] (torch .repeat tiling) — exact.
        const _Float16* mrow = emeanf + (size_t)((n0 + l15) & (BATCH - 1)) * HID;
#pragma unroll
        for (int ks = 0; ks < 4; ++ks) {
            av[ks]    = *(const half8*)(erow + ks * 32 + quad * 8);
            amean[ks] = *(const half8*)(mrow + ks * 32 + quad * 8);
        }
    }

    // ---- v1: t1 = relu(emb @ vw1 + vb1) ----
    floatx4 acc;
    {
        float bb = vb1[ct * 16 + l15];
        acc = (floatx4){bb, bb, bb, bb};
    }
#pragma unroll
    for (int ks = 0; ks < 4; ++ks) {
        half8 bfr = *(const half8*)(vw1p + ((size_t)ct * 4 + ks) * 512 + lane * 8);
        acc = __builtin_amdgcn_mfma_f32_16x16x32_f16(av[ks], bfr, acc, 0, 0, 0);
    }
#pragma unroll
    for (int reg = 0; reg < 4; ++reg)
        tAs[quad * 4 + reg][ct * 16 + l15] = (_Float16)fmaxf(acc[reg], 0.f);
    __syncthreads();                                    // barrier 1

    half8 at[4];
#pragma unroll
    for (int ks = 0; ks < 4; ++ks)
        at[ks] = *(const half8*)&tAs[l15][ks * 32 + quad * 8];

    // ---- v2: vals = relu(t1 @ vw2 + vb2), kept in registers ----
    floatx4 vacc;
    {
        float bb = vb2[ct * 16 + l15];
        vacc = (floatx4){bb, bb, bb, bb};
    }
#pragma unroll
    for (int ks = 0; ks < 4; ++ks) {
        half8 bfr = *(const half8*)(vw2p + ((size_t)ct * 4 + ks) * 512 + lane * 8);
        vacc = __builtin_amdgcn_mfma_f32_16x16x32_f16(at[ks], bfr, vacc, 0, 0, 0);
    }

    // ---- a1: ta1 = relu([emb|mean] @ aw1 + ab1), K=256 ----
    floatx4 aacc;
    {
        float bb = ab1[ct * 16 + l15];
        aacc = (floatx4){bb, bb, bb, bb};
    }
#pragma unroll
    for (int ks = 0; ks < 8; ++ks) {
        half8 bfr = *(const half8*)(aw1p + ((size_t)ct * 8 + ks) * 512 + lane * 8);
        half8 a = (ks < 4) ? av[ks] : amean[ks - 4];
        aacc = __builtin_amdgcn_mfma_f32_16x16x32_f16(a, bfr, aacc, 0, 0, 0);
    }
#pragma unroll
    for (int reg = 0; reg < 4; ++reg)
        tBs[quad * 4 + reg][ct * 16 + l15] = (_Float16)fmaxf(aacc[reg], 0.f);
    __syncthreads();                                    // barrier 2

    half8 aa[4];
#pragma unroll
    for (int ks = 0; ks < 4; ++ks)
        aa[ks] = *(const half8*)&tBs[l15][ks * 32 + quad * 8];

    // ---- a2: t2 = relu(ta1 @ aw2 + ab2) -> tCs (3rd buffer: no WAR barrier)
    floatx4 a2acc;
    {
        float bb = ab2[ct * 16 + l15];
        a2acc = (floatx4){bb, bb, bb, bb};
    }
#pragma unroll
    for (int ks = 0; ks < 4; ++ks) {
        half8 bfr = *(const half8*)(aw2p + ((size_t)ct * 4 + ks) * 512 + lane * 8);
        a2acc = __builtin_amdgcn_mfma_f32_16x16x32_f16(aa[ks], bfr, a2acc, 0, 0, 0);
    }
#pragma unroll
    for (int reg = 0; reg < 4; ++reg)
        tCs[quad * 4 + reg][ct * 16 + l15] = (_Float16)fmaxf(a2acc[reg], 0.f);
    __syncthreads();                                    // barrier 3

    // ---- scores + softmax entirely in wave 0 (shfl reductions) ----
    if (wave == 0) {
        int r = lane >> 2, q4 = lane & 3;   // 16 rows x 4 lanes
        float p = 0.f;
#pragma unroll
        for (int c = 0; c < 4; ++c) {
            half8 v = *(const half8*)&tCs[r][q4 * 32 + c * 8];
            float4 w0 = *(const float4*)(aw3 + q4 * 32 + c * 8);
            float4 w1 = *(const float4*)(aw3 + q4 * 32 + c * 8 + 4);
            p += (float)v[0] * w0.x + (float)v[1] * w0.y +
                 (float)v[2] * w0.z + (float)v[3] * w0.w +
                 (float)v[4] * w1.x + (float)v[5] * w1.y +
                 (float)v[6] * w1.z + (float)v[7] * w1.w;
        }
        p += __shfl_xor(p, 1, 64);
        p += __shfl_xor(p, 2, 64);          // all 4 lanes of group r: score[r]
        float s = p + ab3[0];
        float m = s;
#pragma unroll
        for (int off = 4; off < 64; off <<= 1) m = fmaxf(m, __shfl_xor(m, off, 64));
        float e = expf(s - m);
        float S = e;
#pragma unroll
        for (int off = 4; off < 64; off <<= 1) S += __shfl_xor(S, off, 64);
        if (q4 == 0) att[r] = e / S;
    }
    __syncthreads();                                    // barrier 4

    // ---- weighted sum: out[g, col] = sum_a att[a] * vals[a, col] ----
    {
        float p = 0.f;
#pragma unroll
        for (int reg = 0; reg < 4; ++reg)
            p += att[quad * 4 + reg] * fmaxf(vacc[reg], 0.f);
        p += __shfl_xor(p, 16, 64);
        p += __shfl_xor(p, 32, 64);
        if (quad == 0) out[(size_t)g * HID + ct * 16 + l15] = p;
    }
}

// ---------------------------------------------------------------------------
extern "C" void kernel_launch(void* const* d_in, const int* in_sizes, int n_in,
                              void* d_out, int out_size, void* d_ws, size_t ws_size,
                              hipStream_t stream) {
    const float* obs = (const float*)d_in[0];
    const float* lat = (const float*)d_in[1];
    const float* hw1 = (const float*)d_in[2];
    const float* hb1 = (const float*)d_in[3];
    const float* hw2 = (const float*)d_in[4];
    const float* hb2 = (const float*)d_in[5];
    const float* vw1 = (const float*)d_in[6];
    const float* vb1 = (const float*)d_in[7];
    const float* vw2 = (const float*)d_in[8];
    const float* vb2 = (const float*)d_in[9];
    const float* aw1 = (const float*)d_in[10];
    const float* ab1 = (const float*)d_in[11];
    const float* aw2 = (const float*)d_in[12];
    const float* ab2 = (const float*)d_in[13];
    const float* aw3 = (const float*)d_in[14];
    const float* ab3 = (const float*)d_in[15];
    float* out = (float*)d_out;

    char* ws = (char*)d_ws;
    _Float16*  hf     = (_Float16*)ws;  ws += (size_t)NROWS * HID * 2;     // 2 MB
    _Float16*  w2p    = (_Float16*)ws;  ws += (size_t)WCOLS * HID * 2;     // 2 MB
    _Float16*  embf   = (_Float16*)ws;  ws += (size_t)NROWS * HID * 2;     // 2 MB
    _Float16*  emeanf = (_Float16*)ws;  ws += (size_t)BATCH * HID * 2;     // 128 KB
    _Float16*  vw1p   = (_Float16*)ws;  ws += (size_t)HID * HID * 2;       // 32 KB
    _Float16*  vw2p   = (_Float16*)ws;  ws += (size_t)HID * HID * 2;
    _Float16*  aw1p   = (_Float16*)ws;  ws += (size_t)2 * HID * HID * 2;   // 64 KB
    _Float16*  aw2p   = (_Float16*)ws;  ws += (size_t)HID * HID * 2;

    hipLaunchKernelGGL(k_prep, dim3(PACK_BLOCKS + NROWS / 16), dim3(256), 0, stream,
                       obs, lat, hw1, hb1, hw2, vw1, vw2, aw1, aw2,
                       hf, w2p, vw1p, vw2p, aw1p, aw2p);
    hipLaunchKernelGGL(k_hyper_mfma, dim3(512), dim3(512), 0, stream,
                       obs, lat, hf, w2p, hb2, embf, emeanf);
    hipLaunchKernelGGL(k_tail, dim3(BATCH), dim3(512), 0, stream,
                       embf, emeanf, vw1p, vb1, vw2p, vb2,
                       aw1p, ab1, aw2p, ab2, aw3, ab3, out);
}

// Round 9
// 136.426 us; speedup vs baseline: 1.4549x; 1.4549x over previous
//
#include <hip/hip_runtime.h>
#include <hip/hip_bf16.h>
#include <math.h>

// Problem constants (fixed by setup_inputs)
#define BATCH 512
#define NADV  16
#define NROWS (BATCH*NADV)     // 8192
#define DS    32
#define DO    32
#define DIM   64               // DS + DO
#define HID   128
#define WCOLS (DIM*HID)        // 8192 columns of hw2
#define LSTR  136              // padded f16 LDS row stride (2-way bank aliasing)
#define PACK_BLOCKS 276

typedef _Float16 half8 __attribute__((ext_vector_type(8)));
typedef float floatx4 __attribute__((ext_vector_type(4)));

__device__ inline void async_ld16(void* lds, const void* g) {
    __builtin_amdgcn_global_load_lds(
        (const __attribute__((address_space(1))) void*)g,
        (__attribute__((address_space(3))) void*)lds, 16, 0, 0);
}

// ---------------------------------------------------------------------------
// Kernel PREP (fused): blocks [0,276) pack weights into MFMA-native f16
// chunks (coalesced 512-B row reads via LDS tile); blocks [276,788) build
// h = relu(x@hw1+hb1) (x formed in LDS from obs/latent; not materialized).
// Packed layout: chunk(ct,kt)[lane*8+e] = W[kt*32+(lane>>4)*8+e][ct*16+(lane&15)]
// so a wave's B-fragment load is ONE contiguous 1 KB burst.
// ---------------------------------------------------------------------------
__global__ __launch_bounds__(256)
void k_prep(const float* __restrict__ obs, const float* __restrict__ latent,
            const float* __restrict__ hw1, const float* __restrict__ hb1,
            const float* __restrict__ hw2, const float* __restrict__ vw1,
            const float* __restrict__ vw2, const float* __restrict__ aw1,
            const float* __restrict__ aw2,
            _Float16* __restrict__ hf,
            _Float16* __restrict__ w2p, _Float16* __restrict__ vw1p,
            _Float16* __restrict__ vw2p, _Float16* __restrict__ aw1p,
            _Float16* __restrict__ aw2p) {
    __shared__ __align__(16) float smem[32 * 132];   // 16.9 KB
    int b = blockIdx.x;
    int tid = threadIdx.x;
    if (b < PACK_BLOCKS) {
        const float* src; _Float16* dst; int N, Kt, jb, kt;
        if (b < 256)      { src = hw2; dst = w2p;  N = WCOLS; Kt = 4; jb = b >> 2; kt = b & 3; }
        else if (b < 260) { src = vw1; dst = vw1p; N = HID;   Kt = 4; jb = 0; kt = b - 256; }
        else if (b < 264) { src = vw2; dst = vw2p; N = HID;   Kt = 4; jb = 0; kt = b - 260; }
        else if (b < 272) { src = aw1; dst = aw1p; N = HID;   Kt = 8; jb = 0; kt = b - 264; }
        else              { src = aw2; dst = aw2p; N = HID;   Kt = 4; jb = 0; kt = b - 272; }
        // coalesced read: 32 k-rows x 128 j-cols (512 B contiguous per row)
        for (int i = tid; i < 32 * 32; i += 256) {
            int r = i >> 5, c4 = (i & 31) * 4;
            *(float4*)&smem[r * 132 + c4] =
                *(const float4*)(src + (size_t)(kt * 32 + r) * N + jb * 128 + c4);
        }
        __syncthreads();
        // write 8 chunks (ctl 0..7), each 1 KB, fully contiguous stores
        for (int i = tid; i < 8 * 64; i += 256) {
            int ctl = i >> 6, lane = i & 63;
            int ct = jb * 8 + ctl;
            int rbase = (lane >> 4) * 8, cc = ctl * 16 + (lane & 15);
            half8 v;
#pragma unroll
            for (int e = 0; e < 8; ++e) v[e] = (_Float16)smem[(rbase + e) * 132 + cc];
            *(half8*)(dst + ((size_t)ct * Kt + kt) * 512 + lane * 8) = v;
        }
    } else {
        // input_h: 16 rows, h = relu(x @ hw1 + hb1)
        int n0 = (b - PACK_BLOCKS) * 16;
        float* xs = smem;   // [16][DIM]
        for (int idx = tid; idx < 16 * DIM; idx += 256) {
            int r = idx >> 6, d = idx & 63;
            int n = n0 + r;
            // reference pairs obs[n % B] with latent_flat[n] (torch .repeat
            // tiles the batch dim; reshape(-1,DO) row-major) — exact.
            xs[r * DIM + d] = (d < DS) ? obs[(n & (BATCH - 1)) * DS + d]
                                       : latent[(size_t)n * DO + (d - DS)];
        }
        __syncthreads();
        int j = tid & 127, hh = tid >> 7;   // hh: rows hh*8..+8
        float acc[8];
        float bb = hb1[j];
#pragma unroll
        for (int r = 0; r < 8; ++r) acc[r] = bb;
        for (int d = 0; d < DIM; ++d) {
            float w = hw1[d * HID + j];
#pragma unroll
            for (int r = 0; r < 8; ++r)
                acc[r] = fmaf(xs[(hh * 8 + r) * DIM + d], w, acc[r]);
        }
#pragma unroll
        for (int r = 0; r < 8; ++r)
            hf[(size_t)(n0 + hh * 8 + r) * HID + j] = (_Float16)fmaxf(acc[r], 0.f);
    }
}

// ---------------------------------------------------------------------------
// Kernel B: block = 128 rows x 16 emb-cols x ALL 64 d (d-reduce block-local).
// Single-buffer 32 KB LDS; launch_bounds(512,4): VGPR cap 128 (natural ~64-80,
// NO spill — r8's (512,8) forced VGPR=32 + 300 MB scratch spill traffic).
// Occupancy: LDS allows 5 blocks/CU, VGPR ~7 waves/SIMD -> 3-4 blocks/CU;
// barrier drains hidden by other resident blocks (m114 co-schedule).
// x/bias per-iter direct from L2-warm global. Grid = 64 rt x 8 jt.
// ---------------------------------------------------------------------------
__global__ __launch_bounds__(512, 4)
void k_hyper_mfma(const float* __restrict__ obs, const float* __restrict__ latent,
                  const _Float16* __restrict__ hf, const _Float16* __restrict__ w2p,
                  const float* __restrict__ hb2,
                  _Float16* __restrict__ embf, _Float16* __restrict__ emeanf) {
    __shared__ __align__(16) _Float16 Bs[8][4][512];  // 32 KB single buffer
    int b  = blockIdx.x;
    int jt = b & 7;          // emb col-tile (16 cols) — XCD-aligned B reuse
    int rt = b >> 3;         // row-tile: rows [rt*128, +128)
    int n0 = rt * 128;
    int j0 = jt * 16;
    int tid = threadIdx.x;
    int wave = tid >> 6, lane = tid & 63;
    int l15 = lane & 15, quad = lane >> 4;
    int row_lo = n0 + wave * 16 + quad * 4;   // this lane's 4 C-rows

    // A fragments: wave w owns rows [n0+w*16, +16) (= batch rt*8+w)
    half8 af[4];
    {
        const _Float16* arow = hf + (size_t)(n0 + wave * 16 + l15) * HID;
#pragma unroll
        for (int ks = 0; ks < 4; ++ks)
            af[ks] = *(const half8*)(arow + ks * 32 + quad * 8);
    }

    float emb_acc[4] = {0.f, 0.f, 0.f, 0.f};

#pragma unroll
    for (int d8 = 0; d8 < 8; ++d8) {
        {   // stage B: wave w stages d-tile (d8*8+w)'s chunk as 4 x 1 KB bursts
            int ct = (d8 * 8 + wave) * 8 + jt;
            const _Float16* src = w2p + (size_t)ct * 2048 + lane * 8;
            _Float16* dst = &Bs[wave][0][0];
#pragma unroll
            for (int kt = 0; kt < 4; ++kt)
                async_ld16(dst + kt * 512, src + kt * 512);
        }
        __syncthreads();   // DMA drained; prev iter's consumers done

        // x for this iter: 2 float4 per row, quad-broadcast (16 lanes share)
        float xr[4][8];
#pragma unroll
        for (int r = 0; r < 4; ++r) {
            int row = row_lo + r;
            const float* p = (d8 < 4)
                ? obs + (size_t)(row & (BATCH - 1)) * DS + d8 * 8
                : latent + (size_t)row * DO + (d8 - 4) * 8;
            float4 t0 = *(const float4*)p;
            float4 t1 = *(const float4*)(p + 4);
            xr[r][0] = t0.x; xr[r][1] = t0.y; xr[r][2] = t0.z; xr[r][3] = t0.w;
            xr[r][4] = t1.x; xr[r][5] = t1.y; xr[r][6] = t1.z; xr[r][7] = t1.w;
        }

#pragma unroll
        for (int dd = 0; dd < 8; ++dd) {
            int d = d8 * 8 + dd;
            float bb = hb2[d * HID + j0 + l15];   // coalesced 64-B wave load
            floatx4 acc = {bb, bb, bb, bb};
#pragma unroll
            for (int ks = 0; ks < 4; ++ks) {
                half8 bfr = *(const half8*)&Bs[dd][ks][lane * 8];
                acc = __builtin_amdgcn_mfma_f32_16x16x32_f16(af[ks], bfr, acc, 0, 0, 0);
            }
            // D: row = wave*16 + quad*4 + reg, col = j0 + l15
#pragma unroll
            for (int reg = 0; reg < 4; ++reg)
                emb_acc[reg] = fmaf(xr[reg][dd], fmaxf(acc[reg], 0.f), emb_acc[reg]);
        }
        __syncthreads();   // done consuming Bs; safe to restage
    }

    // epilogue: tanh -> embf; wave = one batch -> column means direct
    float e[4];
#pragma unroll
    for (int reg = 0; reg < 4; ++reg) {
        e[reg] = tanhf(emb_acc[reg]);
        embf[(size_t)(n0 + wave * 16 + quad * 4 + reg) * HID + j0 + l15] =
            (_Float16)e[reg];
    }
    float s = e[0] + e[1] + e[2] + e[3];
    s += __shfl_xor(s, 16, 64);
    s += __shfl_xor(s, 32, 64);
    if (quad == 0)
        emeanf[(size_t)(rt * 8 + wave) * HID + j0 + l15] = (_Float16)(s * (1.f / 16));
}

// ---------------------------------------------------------------------------
// Kernel T (fused tail), 512 blocks x 16 rows (1 softmax group each).
// 4 barriers total: A-frags load DIRECT from global (no LDS stage);
// a2 writes a third buffer (no WAR barrier); scores+softmax in wave 0
// via shfl (no scr/satt LDS stages).
// ---------------------------------------------------------------------------
__global__ __launch_bounds__(512, 4)
void k_tail(const _Float16* __restrict__ embf, const _Float16* __restrict__ emeanf,
            const _Float16* __restrict__ vw1p, const float* __restrict__ vb1,
            const _Float16* __restrict__ vw2p, const float* __restrict__ vb2,
            const _Float16* __restrict__ aw1p, const float* __restrict__ ab1,
            const _Float16* __restrict__ aw2p, const float* __restrict__ ab2,
            const float* __restrict__ aw3, const float* __restrict__ ab3,
            float* __restrict__ out) {
    __shared__ _Float16 tAs[16][LSTR];
    __shared__ _Float16 tBs[16][LSTR];
    __shared__ _Float16 tCs[16][LSTR];
    __shared__ float att[16];
    int g = blockIdx.x;       // batch 0..511
    int n0 = g * 16;
    int tid = threadIdx.x;
    int wave = tid >> 6, lane = tid & 63, l15 = lane & 15, quad = lane >> 4;
    int ct = wave;            // wave owns col-tile ct of 8

    // A-fragments direct from global (L2-warm): row = l15, 16-B chunk by quad
    half8 av[4], amean[4];
    {
        const _Float16* erow = embf + (size_t)(n0 + l15) * HID;
        // mean_rep[n] = emb_mean[n % 512] (torch .repeat tiling) — exact.
        const _Float16* mrow = emeanf + (size_t)((n0 + l15) & (BATCH - 1)) * HID;
#pragma unroll
        for (int ks = 0; ks < 4; ++ks) {
            av[ks]    = *(const half8*)(erow + ks * 32 + quad * 8);
            amean[ks] = *(const half8*)(mrow + ks * 32 + quad * 8);
        }
    }

    // ---- v1: t1 = relu(emb @ vw1 + vb1) ----
    floatx4 acc;
    {
        float bb = vb1[ct * 16 + l15];
        acc = (floatx4){bb, bb, bb, bb};
    }
#pragma unroll
    for (int ks = 0; ks < 4; ++ks) {
        half8 bfr = *(const half8*)(vw1p + ((size_t)ct * 4 + ks) * 512 + lane * 8);
        acc = __builtin_amdgcn_mfma_f32_16x16x32_f16(av[ks], bfr, acc, 0, 0, 0);
    }
#pragma unroll
    for (int reg = 0; reg < 4; ++reg)
        tAs[quad * 4 + reg][ct * 16 + l15] = (_Float16)fmaxf(acc[reg], 0.f);
    __syncthreads();                                    // barrier 1

    half8 at[4];
#pragma unroll
    for (int ks = 0; ks < 4; ++ks)
        at[ks] = *(const half8*)&tAs[l15][ks * 32 + quad * 8];

    // ---- v2: vals = relu(t1 @ vw2 + vb2), kept in registers ----
    floatx4 vacc;
    {
        float bb = vb2[ct * 16 + l15];
        vacc = (floatx4){bb, bb, bb, bb};
    }
#pragma unroll
    for (int ks = 0; ks < 4; ++ks) {
        half8 bfr = *(const half8*)(vw2p + ((size_t)ct * 4 + ks) * 512 + lane * 8);
        vacc = __builtin_amdgcn_mfma_f32_16x16x32_f16(at[ks], bfr, vacc, 0, 0, 0);
    }

    // ---- a1: ta1 = relu([emb|mean] @ aw1 + ab1), K=256 ----
    floatx4 aacc;
    {
        float bb = ab1[ct * 16 + l15];
        aacc = (floatx4){bb, bb, bb, bb};
    }
#pragma unroll
    for (int ks = 0; ks < 8; ++ks) {
        half8 bfr = *(const half8*)(aw1p + ((size_t)ct * 8 + ks) * 512 + lane * 8);
        half8 a = (ks < 4) ? av[ks] : amean[ks - 4];
        aacc = __builtin_amdgcn_mfma_f32_16x16x32_f16(a, bfr, aacc, 0, 0, 0);
    }
#pragma unroll
    for (int reg = 0; reg < 4; ++reg)
        tBs[quad * 4 + reg][ct * 16 + l15] = (_Float16)fmaxf(aacc[reg], 0.f);
    __syncthreads();                                    // barrier 2

    half8 aa[4];
#pragma unroll
    for (int ks = 0; ks < 4; ++ks)
        aa[ks] = *(const half8*)&tBs[l15][ks * 32 + quad * 8];

    // ---- a2: t2 = relu(ta1 @ aw2 + ab2) -> tCs (3rd buffer: no WAR barrier)
    floatx4 a2acc;
    {
        float bb = ab2[ct * 16 + l15];
        a2acc = (floatx4){bb, bb, bb, bb};
    }
#pragma unroll
    for (int ks = 0; ks < 4; ++ks) {
        half8 bfr = *(const half8*)(aw2p + ((size_t)ct * 4 + ks) * 512 + lane * 8);
        a2acc = __builtin_amdgcn_mfma_f32_16x16x32_f16(aa[ks], bfr, a2acc, 0, 0, 0);
    }
#pragma unroll
    for (int reg = 0; reg < 4; ++reg)
        tCs[quad * 4 + reg][ct * 16 + l15] = (_Float16)fmaxf(a2acc[reg], 0.f);
    __syncthreads();                                    // barrier 3

    // ---- scores + softmax entirely in wave 0 (shfl reductions) ----
    if (wave == 0) {
        int r = lane >> 2, q4 = lane & 3;   // 16 rows x 4 lanes
        float p = 0.f;
#pragma unroll
        for (int c = 0; c < 4; ++c) {
            half8 v = *(const half8*)&tCs[r][q4 * 32 + c * 8];
            float4 w0 = *(const float4*)(aw3 + q4 * 32 + c * 8);
            float4 w1 = *(const float4*)(aw3 + q4 * 32 + c * 8 + 4);
            p += (float)v[0] * w0.x + (float)v[1] * w0.y +
                 (float)v[2] * w0.z + (float)v[3] * w0.w +
                 (float)v[4] * w1.x + (float)v[5] * w1.y +
                 (float)v[6] * w1.z + (float)v[7] * w1.w;
        }
        p += __shfl_xor(p, 1, 64);
        p += __shfl_xor(p, 2, 64);          // all 4 lanes of group r: score[r]
        float s = p + ab3[0];
        float m = s;
#pragma unroll
        for (int off = 4; off < 64; off <<= 1) m = fmaxf(m, __shfl_xor(m, off, 64));
        float e = expf(s - m);
        float S = e;
#pragma unroll
        for (int off = 4; off < 64; off <<= 1) S += __shfl_xor(S, off, 64);
        if (q4 == 0) att[r] = e / S;
    }
    __syncthreads();                                    // barrier 4

    // ---- weighted sum: out[g, col] = sum_a att[a] * vals[a, col] ----
    {
        float p = 0.f;
#pragma unroll
        for (int reg = 0; reg < 4; ++reg)
            p += att[quad * 4 + reg] * fmaxf(vacc[reg], 0.f);
        p += __shfl_xor(p, 16, 64);
        p += __shfl_xor(p, 32, 64);
        if (quad == 0) out[(size_t)g * HID + ct * 16 + l15] = p;
    }
}

// ---------------------------------------------------------------------------
extern "C" void kernel_launch(void* const* d_in, const int* in_sizes, int n_in,
                              void* d_out, int out_size, void* d_ws, size_t ws_size,
                              hipStream_t stream) {
    const float* obs = (const float*)d_in[0];
    const float* lat = (const float*)d_in[1];
    const float* hw1 = (const float*)d_in[2];
    const float* hb1 = (const float*)d_in[3];
    const float* hw2 = (const float*)d_in[4];
    const float* hb2 = (const float*)d_in[5];
    const float* vw1 = (const float*)d_in[6];
    const float* vb1 = (const float*)d_in[7];
    const float* vw2 = (const float*)d_in[8];
    const float* vb2 = (const float*)d_in[9];
    const float* aw1 = (const float*)d_in[10];
    const float* ab1 = (const float*)d_in[11];
    const float* aw2 = (const float*)d_in[12];
    const float* ab2 = (const float*)d_in[13];
    const float* aw3 = (const float*)d_in[14];
    const float* ab3 = (const float*)d_in[15];
    float* out = (float*)d_out;

    char* ws = (char*)d_ws;
    _Float16*  hf     = (_Float16*)ws;  ws += (size_t)NROWS * HID * 2;     // 2 MB
    _Float16*  w2p    = (_Float16*)ws;  ws += (size_t)WCOLS * HID * 2;     // 2 MB
    _Float16*  embf   = (_Float16*)ws;  ws += (size_t)NROWS * HID * 2;     // 2 MB
    _Float16*  emeanf = (_Float16*)ws;  ws += (size_t)BATCH * HID * 2;     // 128 KB
    _Float16*  vw1p   = (_Float16*)ws;  ws += (size_t)HID * HID * 2;       // 32 KB
    _Float16*  vw2p   = (_Float16*)ws;  ws += (size_t)HID * HID * 2;
    _Float16*  aw1p   = (_Float16*)ws;  ws += (size_t)2 * HID * HID * 2;   // 64 KB
    _Float16*  aw2p   = (_Float16*)ws;  ws += (size_t)HID * HID * 2;

    hipLaunchKernelGGL(k_prep, dim3(PACK_BLOCKS + NROWS / 16), dim3(256), 0, stream,
                       obs, lat, hw1, hb1, hw2, vw1, vw2, aw1, aw2,
                       hf, w2p, vw1p, vw2p, aw1p, aw2p);
    hipLaunchKernelGGL(k_hyper_mfma, dim3(512), dim3(512), 0, stream,
                       obs, lat, hf, w2p, hb2, embf, emeanf);
    hipLaunchKernelGGL(k_tail, dim3(BATCH), dim3(512), 0, stream,
                       embf, emeanf, vw1p, vb1, vw2p, vb2,
                       aw1p, ab1, aw2p, ab2, aw3, ab3, out);
}

// Round 10
// 133.212 us; speedup vs baseline: 1.4900x; 1.0241x over previous
//
#include <hip/hip_runtime.h>
#include <hip/hip_bf16.h>
#include <math.h>

// Problem constants (fixed by setup_inputs)
#define BATCH 512
#define NADV  16
#define NROWS (BATCH*NADV)     // 8192
#define DS    32
#define DO    32
#define DIM   64               // DS + DO
#define HID   128
#define WCOLS (DIM*HID)        // 8192 columns of hw2
#define LSTR  136              // padded f16 LDS row stride (2-way bank aliasing)
#define PACK_BLOCKS 278

typedef _Float16 half8 __attribute__((ext_vector_type(8)));
typedef float floatx4 __attribute__((ext_vector_type(4)));

__device__ inline void async_ld16(void* lds, const void* g) {
    __builtin_amdgcn_global_load_lds(
        (const __attribute__((address_space(1))) void*)g,
        (__attribute__((address_space(3))) void*)lds, 16, 0, 0);
}

// ---------------------------------------------------------------------------
// Kernel PREP (pack-only now, 278 blocks ~ 1/CU): packs hw2/vw1/vw2/aw1/aw2/
// hw1 into MFMA-native f16 chunks so a wave's B-fragment load is ONE
// contiguous 1 KB burst.
// chunk(ct,kt)[lane*8+e] = W[kt*32+(lane>>4)*8+e][ct*16+(lane&15)]
// ---------------------------------------------------------------------------
__global__ __launch_bounds__(256)
void k_prep(const float* __restrict__ hw1, const float* __restrict__ hw2,
            const float* __restrict__ vw1, const float* __restrict__ vw2,
            const float* __restrict__ aw1, const float* __restrict__ aw2,
            _Float16* __restrict__ hw1p, _Float16* __restrict__ w2p,
            _Float16* __restrict__ vw1p, _Float16* __restrict__ vw2p,
            _Float16* __restrict__ aw1p, _Float16* __restrict__ aw2p) {
    __shared__ __align__(16) float smem[32 * 132];   // 16.9 KB
    int b = blockIdx.x;
    int tid = threadIdx.x;
    const float* src; _Float16* dst; int N, Kt, jb, kt;
    if (b < 256)      { src = hw2; dst = w2p;  N = WCOLS; Kt = 4; jb = b >> 2; kt = b & 3; }
    else if (b < 260) { src = vw1; dst = vw1p; N = HID;   Kt = 4; jb = 0; kt = b - 256; }
    else if (b < 264) { src = vw2; dst = vw2p; N = HID;   Kt = 4; jb = 0; kt = b - 260; }
    else if (b < 272) { src = aw1; dst = aw1p; N = HID;   Kt = 8; jb = 0; kt = b - 264; }
    else if (b < 276) { src = aw2; dst = aw2p; N = HID;   Kt = 4; jb = 0; kt = b - 272; }
    else              { src = hw1; dst = hw1p; N = HID;   Kt = 2; jb = 0; kt = b - 276; }
    // coalesced read: 32 k-rows x 128 j-cols (512 B contiguous per row)
    for (int i = tid; i < 32 * 32; i += 256) {
        int r = i >> 5, c4 = (i & 31) * 4;
        *(float4*)&smem[r * 132 + c4] =
            *(const float4*)(src + (size_t)(kt * 32 + r) * N + jb * 128 + c4);
    }
    __syncthreads();
    // write 8 chunks (ctl 0..7), each 1 KB, fully contiguous stores
    for (int i = tid; i < 8 * 64; i += 256) {
        int ctl = i >> 6, lane = i & 63;
        int ct = jb * 8 + ctl;
        int rbase = (lane >> 4) * 8, cc = ctl * 16 + (lane & 15);
        half8 v;
#pragma unroll
        for (int e = 0; e < 8; ++e) v[e] = (_Float16)smem[(rbase + e) * 132 + cc];
        *(half8*)(dst + ((size_t)ct * Kt + kt) * 512 + lane * 8) = v;
    }
}

// ---------------------------------------------------------------------------
// Kernel B: block = 128 rows x 16 emb-cols x ALL 64 d (d-reduce block-local).
// NEW: h = relu(x@hw1+hb1) computed IN-KERNEL via MFMA (16 MFMA/wave,
// redundant x8 across jt but ~0.3us device-wide) -> kills the input_h
// sub-kernel and the hf global round-trip. D-layout -> A-layout via LDS
// (hs, padded stride 136), whose memory is then reused as the Bs staging
// buffer (union, 34 KB -> still 4 blocks/CU with launch_bounds(512,4);
// r8 lesson: never cap VGPR below need - 300 MB spill).
// Single-buffer staging + m114 inter-block overlap (r7 lesson: explicit
// dbuf at 2 blocks/CU regresses). Grid = 64 rt x 8 jt (jt=b&7: XCD-local B).
// ---------------------------------------------------------------------------
__global__ __launch_bounds__(512, 4)
void k_hyper_mfma(const float* __restrict__ obs, const float* __restrict__ latent,
                  const _Float16* __restrict__ hw1p, const float* __restrict__ hb1,
                  const _Float16* __restrict__ w2p, const float* __restrict__ hb2,
                  _Float16* __restrict__ embf, _Float16* __restrict__ emeanf) {
    __shared__ __align__(16) char lds_raw[128 * LSTR * 2];  // 34 KB union
    _Float16 (*hs)[LSTR] = (_Float16(*)[LSTR])lds_raw;      // phase 1: h
    _Float16* Bs = (_Float16*)lds_raw;                      // phase 2: B staging
    int b  = blockIdx.x;
    int jt = b & 7;          // emb col-tile (16 cols) — XCD-aligned B reuse
    int rt = b >> 3;         // row-tile: rows [rt*128, +128)
    int n0 = rt * 128;
    int j0 = jt * 16;
    int tid = threadIdx.x;
    int wave = tid >> 6, lane = tid & 63;
    int l15 = lane & 15, quad = lane >> 4;
    int row_lo = n0 + wave * 16 + quad * 4;   // this lane's 4 C-rows (epilogue)

    // ---- phase 1: h = relu(x @ hw1 + hb1) for this block's 128 rows ----
    {
        int row = n0 + wave * 16 + l15;
        // x A-frags: ks2=0 -> k 0..31 = obs[row%512]; ks2=1 -> k 32..63 = latent[row]
        half8 ax[2];
        {
            const float* p0 = obs + (size_t)(row & (BATCH - 1)) * DS + quad * 8;
            const float* p1 = latent + (size_t)row * DO + quad * 8;
            float4 a0 = *(const float4*)p0, b0 = *(const float4*)(p0 + 4);
            float4 a1 = *(const float4*)p1, b1 = *(const float4*)(p1 + 4);
            ax[0][0] = (_Float16)a0.x; ax[0][1] = (_Float16)a0.y;
            ax[0][2] = (_Float16)a0.z; ax[0][3] = (_Float16)a0.w;
            ax[0][4] = (_Float16)b0.x; ax[0][5] = (_Float16)b0.y;
            ax[0][6] = (_Float16)b0.z; ax[0][7] = (_Float16)b0.w;
            ax[1][0] = (_Float16)a1.x; ax[1][1] = (_Float16)a1.y;
            ax[1][2] = (_Float16)a1.z; ax[1][3] = (_Float16)a1.w;
            ax[1][4] = (_Float16)b1.x; ax[1][5] = (_Float16)b1.y;
            ax[1][6] = (_Float16)b1.z; ax[1][7] = (_Float16)b1.w;
        }
#pragma unroll
        for (int ct2 = 0; ct2 < 8; ++ct2) {
            float bb = hb1[ct2 * 16 + l15];
            floatx4 hacc = {bb, bb, bb, bb};
#pragma unroll
            for (int ks2 = 0; ks2 < 2; ++ks2) {
                half8 bfr = *(const half8*)(hw1p + ((size_t)ct2 * 2 + ks2) * 512 + lane * 8);
                hacc = __builtin_amdgcn_mfma_f32_16x16x32_f16(ax[ks2], bfr, hacc, 0, 0, 0);
            }
            // D: row = wave*16 + quad*4 + reg, col = ct2*16 + l15
#pragma unroll
            for (int reg = 0; reg < 4; ++reg)
                hs[wave * 16 + quad * 4 + reg][ct2 * 16 + l15] =
                    (_Float16)fmaxf(hacc[reg], 0.f);
        }
    }
    __syncthreads();   // h complete in LDS

    // A fragments for the main GEMM (from LDS, padded stride)
    half8 af[4];
#pragma unroll
    for (int ks = 0; ks < 4; ++ks)
        af[ks] = *(const half8*)&hs[wave * 16 + l15][ks * 32 + quad * 8];
    __syncthreads();   // all af reads done -> safe to DMA over hs (as Bs)

    float emb_acc[4] = {0.f, 0.f, 0.f, 0.f};

#pragma unroll
    for (int d8 = 0; d8 < 8; ++d8) {
        {   // stage B: wave w stages d-tile (d8*8+w)'s chunk as 4 x 1 KB bursts
            int ct = (d8 * 8 + wave) * 8 + jt;
            const _Float16* src = w2p + (size_t)ct * 2048 + lane * 8;
            _Float16* dst = Bs + (size_t)wave * 2048;
#pragma unroll
            for (int kt = 0; kt < 4; ++kt)
                async_ld16(dst + kt * 512, src + kt * 512);
        }
        __syncthreads();   // DMA drained; prev iter's consumers done

        // x for this iter: 2 float4 per row, quad-broadcast (16 lanes share)
        float xr[4][8];
#pragma unroll
        for (int r = 0; r < 4; ++r) {
            int row = row_lo + r;
            const float* p = (d8 < 4)
                ? obs + (size_t)(row & (BATCH - 1)) * DS + d8 * 8
                : latent + (size_t)row * DO + (d8 - 4) * 8;
            float4 t0 = *(const float4*)p;
            float4 t1 = *(const float4*)(p + 4);
            xr[r][0] = t0.x; xr[r][1] = t0.y; xr[r][2] = t0.z; xr[r][3] = t0.w;
            xr[r][4] = t1.x; xr[r][5] = t1.y; xr[r][6] = t1.z; xr[r][7] = t1.w;
        }

#pragma unroll
        for (int dd = 0; dd < 8; ++dd) {
            int d = d8 * 8 + dd;
            float bb = hb2[d * HID + j0 + l15];   // coalesced 64-B wave load
            floatx4 acc = {bb, bb, bb, bb};
#pragma unroll
            for (int ks = 0; ks < 4; ++ks) {
                half8 bfr = *(const half8*)(Bs + ((size_t)dd * 4 + ks) * 512 + lane * 8);
                acc = __builtin_amdgcn_mfma_f32_16x16x32_f16(af[ks], bfr, acc, 0, 0, 0);
            }
            // D: row = wave*16 + quad*4 + reg, col = j0 + l15
#pragma unroll
            for (int reg = 0; reg < 4; ++reg)
                emb_acc[reg] = fmaf(xr[reg][dd], fmaxf(acc[reg], 0.f), emb_acc[reg]);
        }
        __syncthreads();   // done consuming Bs; safe to restage
    }

    // epilogue: tanh -> embf; wave = one batch -> column means direct
    float e[4];
#pragma unroll
    for (int reg = 0; reg < 4; ++reg) {
        e[reg] = tanhf(emb_acc[reg]);
        embf[(size_t)(n0 + wave * 16 + quad * 4 + reg) * HID + j0 + l15] =
            (_Float16)e[reg];
    }
    float s = e[0] + e[1] + e[2] + e[3];
    s += __shfl_xor(s, 16, 64);
    s += __shfl_xor(s, 32, 64);
    if (quad == 0)
        emeanf[(size_t)(rt * 8 + wave) * HID + j0 + l15] = (_Float16)(s * (1.f / 16));
}

// ---------------------------------------------------------------------------
// Kernel T (fused tail), 512 blocks x 16 rows (1 softmax group each).
// 4 barriers total: A-frags load DIRECT from global (L2-warm);
// a2 writes a third buffer (no WAR barrier); scores+softmax in wave 0
// via shfl (no scr/satt LDS stages).
// ---------------------------------------------------------------------------
__global__ __launch_bounds__(512, 4)
void k_tail(const _Float16* __restrict__ embf, const _Float16* __restrict__ emeanf,
            const _Float16* __restrict__ vw1p, const float* __restrict__ vb1,
            const _Float16* __restrict__ vw2p, const float* __restrict__ vb2,
            const _Float16* __restrict__ aw1p, const float* __restrict__ ab1,
            const _Float16* __restrict__ aw2p, const float* __restrict__ ab2,
            const float* __restrict__ aw3, const float* __restrict__ ab3,
            float* __restrict__ out) {
    __shared__ _Float16 tAs[16][LSTR];
    __shared__ _Float16 tBs[16][LSTR];
    __shared__ _Float16 tCs[16][LSTR];
    __shared__ float att[16];
    int g = blockIdx.x;       // batch 0..511
    int n0 = g * 16;
    int tid = threadIdx.x;
    int wave = tid >> 6, lane = tid & 63, l15 = lane & 15, quad = lane >> 4;
    int ct = wave;            // wave owns col-tile ct of 8

    // A-fragments direct from global (L2-warm): row = l15, 16-B chunk by quad
    half8 av[4], amean[4];
    {
        const _Float16* erow = embf + (size_t)(n0 + l15) * HID;
        // mean_rep[n] = emb_mean[n % 512] (torch .repeat tiling) — exact.
        const _Float16* mrow = emeanf + (size_t)((n0 + l15) & (BATCH - 1)) * HID;
#pragma unroll
        for (int ks = 0; ks < 4; ++ks) {
            av[ks]    = *(const half8*)(erow + ks * 32 + quad * 8);
            amean[ks] = *(const half8*)(mrow + ks * 32 + quad * 8);
        }
    }

    // ---- v1: t1 = relu(emb @ vw1 + vb1) ----
    floatx4 acc;
    {
        float bb = vb1[ct * 16 + l15];
        acc = (floatx4){bb, bb, bb, bb};
    }
#pragma unroll
    for (int ks = 0; ks < 4; ++ks) {
        half8 bfr = *(const half8*)(vw1p + ((size_t)ct * 4 + ks) * 512 + lane * 8);
        acc = __builtin_amdgcn_mfma_f32_16x16x32_f16(av[ks], bfr, acc, 0, 0, 0);
    }
#pragma unroll
    for (int reg = 0; reg < 4; ++reg)
        tAs[quad * 4 + reg][ct * 16 + l15] = (_Float16)fmaxf(acc[reg], 0.f);
    __syncthreads();                                    // barrier 1

    half8 at[4];
#pragma unroll
    for (int ks = 0; ks < 4; ++ks)
        at[ks] = *(const half8*)&tAs[l15][ks * 32 + quad * 8];

    // ---- v2: vals = relu(t1 @ vw2 + vb2), kept in registers ----
    floatx4 vacc;
    {
        float bb = vb2[ct * 16 + l15];
        vacc = (floatx4){bb, bb, bb, bb};
    }
#pragma unroll
    for (int ks = 0; ks < 4; ++ks) {
        half8 bfr = *(const half8*)(vw2p + ((size_t)ct * 4 + ks) * 512 + lane * 8);
        vacc = __builtin_amdgcn_mfma_f32_16x16x32_f16(at[ks], bfr, vacc, 0, 0, 0);
    }

    // ---- a1: ta1 = relu([emb|mean] @ aw1 + ab1), K=256 ----
    floatx4 aacc;
    {
        float bb = ab1[ct * 16 + l15];
        aacc = (floatx4){bb, bb, bb, bb};
    }
#pragma unroll
    for (int ks = 0; ks < 8; ++ks) {
        half8 bfr = *(const half8*)(aw1p + ((size_t)ct * 8 + ks) * 512 + lane * 8);
        half8 a = (ks < 4) ? av[ks] : amean[ks - 4];
        aacc = __builtin_amdgcn_mfma_f32_16x16x32_f16(a, bfr, aacc, 0, 0, 0);
    }
#pragma unroll
    for (int reg = 0; reg < 4; ++reg)
        tBs[quad * 4 + reg][ct * 16 + l15] = (_Float16)fmaxf(aacc[reg], 0.f);
    __syncthreads();                                    // barrier 2

    half8 aa[4];
#pragma unroll
    for (int ks = 0; ks < 4; ++ks)
        aa[ks] = *(const half8*)&tBs[l15][ks * 32 + quad * 8];

    // ---- a2: t2 = relu(ta1 @ aw2 + ab2) -> tCs (3rd buffer: no WAR barrier)
    floatx4 a2acc;
    {
        float bb = ab2[ct * 16 + l15];
        a2acc = (floatx4){bb, bb, bb, bb};
    }
#pragma unroll
    for (int ks = 0; ks < 4; ++ks) {
        half8 bfr = *(const half8*)(aw2p + ((size_t)ct * 4 + ks) * 512 + lane * 8);
        a2acc = __builtin_amdgcn_mfma_f32_16x16x32_f16(aa[ks], bfr, a2acc, 0, 0, 0);
    }
#pragma unroll
    for (int reg = 0; reg < 4; ++reg)
        tCs[quad * 4 + reg][ct * 16 + l15] = (_Float16)fmaxf(a2acc[reg], 0.f);
    __syncthreads();                                    // barrier 3

    // ---- scores + softmax entirely in wave 0 (shfl reductions) ----
    if (wave == 0) {
        int r = lane >> 2, q4 = lane & 3;   // 16 rows x 4 lanes
        float p = 0.f;
#pragma unroll
        for (int c = 0; c < 4; ++c) {
            half8 v = *(const half8*)&tCs[r][q4 * 32 + c * 8];
            float4 w0 = *(const float4*)(aw3 + q4 * 32 + c * 8);
            float4 w1 = *(const float4*)(aw3 + q4 * 32 + c * 8 + 4);
            p += (float)v[0] * w0.x + (float)v[1] * w0.y +
                 (float)v[2] * w0.z + (float)v[3] * w0.w +
                 (float)v[4] * w1.x + (float)v[5] * w1.y +
                 (float)v[6] * w1.z + (float)v[7] * w1.w;
        }
        p += __shfl_xor(p, 1, 64);
        p += __shfl_xor(p, 2, 64);          // all 4 lanes of group r: score[r]
        float s = p + ab3[0];
        float m = s;
#pragma unroll
        for (int off = 4; off < 64; off <<= 1) m = fmaxf(m, __shfl_xor(m, off, 64));
        float e = expf(s - m);
        float S = e;
#pragma unroll
        for (int off = 4; off < 64; off <<= 1) S += __shfl_xor(S, off, 64);
        if (q4 == 0) att[r] = e / S;
    }
    __syncthreads();                                    // barrier 4

    // ---- weighted sum: out[g, col] = sum_a att[a] * vals[a, col] ----
    {
        float p = 0.f;
#pragma unroll
        for (int reg = 0; reg < 4; ++reg)
            p += att[quad * 4 + reg] * fmaxf(vacc[reg], 0.f);
        p += __shfl_xor(p, 16, 64);
        p += __shfl_xor(p, 32, 64);
        if (quad == 0) out[(size_t)g * HID + ct * 16 + l15] = p;
    }
}

// ---------------------------------------------------------------------------
extern "C" void kernel_launch(void* const* d_in, const int* in_sizes, int n_in,
                              void* d_out, int out_size, void* d_ws, size_t ws_size,
                              hipStream_t stream) {
    const float* obs = (const float*)d_in[0];
    const float* lat = (const float*)d_in[1];
    const float* hw1 = (const float*)d_in[2];
    const float* hb1 = (const float*)d_in[3];
    const float* hw2 = (const float*)d_in[4];
    const float* hb2 = (const float*)d_in[5];
    const float* vw1 = (const float*)d_in[6];
    const float* vb1 = (const float*)d_in[7];
    const float* vw2 = (const float*)d_in[8];
    const float* vb2 = (const float*)d_in[9];
    const float* aw1 = (const float*)d_in[10];
    const float* ab1 = (const float*)d_in[11];
    const float* aw2 = (const float*)d_in[12];
    const float* ab2 = (const float*)d_in[13];
    const float* aw3 = (const float*)d_in[14];
    const float* ab3 = (const float*)d_in[15];
    float* out = (float*)d_out;

    char* ws = (char*)d_ws;
    _Float16*  w2p    = (_Float16*)ws;  ws += (size_t)WCOLS * HID * 2;     // 2 MB
    _Float16*  embf   = (_Float16*)ws;  ws += (size_t)NROWS * HID * 2;     // 2 MB
    _Float16*  emeanf = (_Float16*)ws;  ws += (size_t)BATCH * HID * 2;     // 128 KB
    _Float16*  hw1p   = (_Float16*)ws;  ws += (size_t)DIM * HID * 2;       // 16 KB
    _Float16*  vw1p   = (_Float16*)ws;  ws += (size_t)HID * HID * 2;       // 32 KB
    _Float16*  vw2p   = (_Float16*)ws;  ws += (size_t)HID * HID * 2;
    _Float16*  aw1p   = (_Float16*)ws;  ws += (size_t)2 * HID * HID * 2;   // 64 KB
    _Float16*  aw2p   = (_Float16*)ws;  ws += (size_t)HID * HID * 2;

    hipLaunchKernelGGL(k_prep, dim3(PACK_BLOCKS), dim3(256), 0, stream,
                       hw1, hw2, vw1, vw2, aw1, aw2,
                       hw1p, w2p, vw1p, vw2p, aw1p, aw2p);
    hipLaunchKernelGGL(k_hyper_mfma, dim3(512), dim3(512), 0, stream,
                       obs, lat, hw1p, hb1, w2p, hb2, embf, emeanf);
    hipLaunchKernelGGL(k_tail, dim3(BATCH), dim3(512), 0, stream,
                       embf, emeanf, vw1p, vb1, vw2p, vb2,
                       aw1p, ab1, aw2p, ab2, aw3, ab3, out);
}